// Round 10
// baseline (49.656 us; speedup 1.0000x reference)
//
#include <hip/hip_runtime.h>

// GHM-C loss, one-pass, register-only, packed-f32 accumulation:
//   q = (c==t) ? -p : p ; e = exp(-|q|) ; bce = max(q,0) + ln(1+e)
//   cthr = #{|q| < ln9, ln4, ln(7/3), ln(3/2)} (monotone) ; bin = q>=0 ? 9-cthr : cthr
//   Packed channels (v_pk_fma_f32): A_i = sum m_i*(v,1), B_i = sum m_i*(sv,sc)
//   with sv = qp?v:-v, sc = qp?1:-1. Counts ride the .y lanes -> no ballots,
//   no popc, zero SALU per element. PhiPre=(Ax+Bx)/2, PloPre=(Ax-Bx)/2,
//   HiPre=(Ay+By)/2, LoPre=(Ay-By)/2; bins by differencing in ghm_final.

#define NROWS 4194304

constexpr int BLOCK = 256;
constexpr int MAXGRID = 2048;
constexpr int STRD = MAXGRID * BLOCK; // 524288 -> exactly 8 rows/thread

typedef float f2 __attribute__((ext_vector_type(2)));

#define GHM_DECL \
    float A0x = 0.f, sumw = 0.f; \
    f2 A1 = {0,0}, A2 = {0,0}, A3 = {0,0}, A4 = {0,0}; \
    f2 B0 = {0,0}, B1 = {0,0}, B2 = {0,0}, B3 = {0,0}, B4 = {0,0};

#define GHM_ELEM(P, CI) { \
        const float q  = ((CI) == t) ? -(P) : (P); \
        const float aq = __builtin_fabsf(q); \
        const float e  = __builtin_amdgcn_exp2f(aq * NLOG2E); \
        const float l  = __builtin_amdgcn_logf(1.0f + e); \
        const float v  = fmaf(l, wln2, w * fmaxf(q, 0.0f)); \
        const bool qp = q >= 0.0f; \
        const bool b0 = aq < T0; \
        const bool b1 = aq < T1; \
        const bool b2 = aq < T2; \
        const bool b3 = aq < T3; \
        f2 v1; v1.x = v;                 v1.y = 1.0f; \
        f2 vs; vs.x = qp ? v : -v;       vs.y = qp ? 1.0f : -1.0f; \
        A0x += v; \
        B0 += vs; \
        f2 mm0; mm0.x = b0 ? 1.0f : 0.0f; mm0.y = mm0.x; \
        f2 mm1; mm1.x = b1 ? 1.0f : 0.0f; mm1.y = mm1.x; \
        f2 mm2; mm2.x = b2 ? 1.0f : 0.0f; mm2.y = mm2.x; \
        f2 mm3; mm3.x = b3 ? 1.0f : 0.0f; mm3.y = mm3.x; \
        A1 = v1 * mm0 + A1;  B1 = vs * mm0 + B1; \
        A2 = v1 * mm1 + A2;  B2 = vs * mm1 + B2; \
        A3 = v1 * mm2 + A3;  B3 = vs * mm2 + B3; \
        A4 = v1 * mm3 + A4;  B4 = vs * mm3 + B4; \
    }

#define GHM_ROW \
        sumw += w; \
        const float wln2 = w * LN2; \
        GHM_ELEM(a.x, 0) GHM_ELEM(a.y, 1) GHM_ELEM(a.z, 2) GHM_ELEM(a.w, 3) \
        GHM_ELEM(b.x, 4) GHM_ELEM(b.y, 5) GHM_ELEM(b.z, 6) GHM_ELEM(b.w, 7)

#define GHM_CONSTS \
    constexpr float NLOG2E = -1.4426950408889634f; \
    constexpr float LN2    = 0.6931471805599453f; \
    constexpr float T0 = 2.1972245773362196f; \
    constexpr float T1 = 1.3862943611198906f; \
    constexpr float T2 = 0.8472978603872037f; \
    constexpr float T3 = 0.4054651081081644f;

// channel order in ws (20 floats per block, 32-float slot):
// [0]=A0x [1..4]=A1x..A4x [5..9]=B0x..B4x [10]=sumw [11..14]=A1y..A4y [15..19]=B0y..B4y
__device__ __forceinline__ void ghm_reduce_store(
    float A0x, f2 A1, f2 A2, f2 A3, f2 A4,
    f2 B0, f2 B1, f2 B2, f2 B3, f2 B4,
    float sumw, float* __restrict__ ws, int tid)
{
    float r20[20];
    r20[0] = A0x;
    r20[1] = A1.x;  r20[2] = A2.x;  r20[3] = A3.x;  r20[4] = A4.x;
    r20[5] = B0.x;  r20[6] = B1.x;  r20[7] = B2.x;  r20[8] = B3.x;  r20[9] = B4.x;
    r20[10] = sumw;
    r20[11] = A1.y; r20[12] = A2.y; r20[13] = A3.y; r20[14] = A4.y;
    r20[15] = B0.y; r20[16] = B1.y; r20[17] = B2.y; r20[18] = B3.y; r20[19] = B4.y;

#pragma unroll
    for (int i = 0; i < 20; ++i) {
        float x = r20[i];
#pragma unroll
        for (int o = 32; o >= 1; o >>= 1) x += __shfl_xor(x, o, 64);
        r20[i] = x;
    }

    __shared__ float red4[4][20];
    const int lane = tid & 63, wv = tid >> 6;
    if (lane == 0) {
#pragma unroll
        for (int i = 0; i < 20; ++i) red4[wv][i] = r20[i];
    }
    __syncthreads();
    if (tid < 20) {
        const float s = red4[0][tid] + red4[1][tid] + red4[2][tid] + red4[3][tid];
        ws[blockIdx.x * 32 + tid] = s;
    }
}

// static kernel: grid == 2048 exactly, 8 rows/thread, guard-free
__global__ __launch_bounds__(BLOCK) void ghm_main_s(
    const float* __restrict__ pred, const int* __restrict__ target,
    const float* __restrict__ weight, float* __restrict__ ws)
{
    __shared__ float wlds[8];
    const int tid = threadIdx.x;
    if (tid < 8) wlds[tid] = weight[tid];
    __syncthreads();

    GHM_DECL
    GHM_CONSTS
    const float4* __restrict__ p4 = reinterpret_cast<const float4*>(pred);
    const int r0 = blockIdx.x * BLOCK + tid;

#pragma unroll 2
    for (int k = 0; k < 8; ++k) {
        const int r = r0 + k * STRD;           // no bounds check: 8*STRD == NROWS
        const float4 a = p4[2 * (size_t)r];
        const float4 b = p4[2 * (size_t)r + 1];
        const int t = target[r];
        const float w = wlds[t];
        GHM_ROW
    }

    ghm_reduce_store(A0x, A1, A2, A3, A4, B0, B1, B2, B3, B4, sumw, ws, tid);
}

// dynamic fallback (any pow2 grid dividing NROWS)
__global__ __launch_bounds__(BLOCK) void ghm_main_d(
    const float* __restrict__ pred, const int* __restrict__ target,
    const float* __restrict__ weight, float* __restrict__ ws)
{
    __shared__ float wlds[8];
    const int tid = threadIdx.x;
    if (tid < 8) wlds[tid] = weight[tid];
    __syncthreads();

    GHM_DECL
    GHM_CONSTS
    const int stride = gridDim.x * BLOCK;
    const float4* __restrict__ p4 = reinterpret_cast<const float4*>(pred);

    for (int r = blockIdx.x * BLOCK + tid; r < NROWS; r += stride) {
        const float4 a = p4[2 * (size_t)r];
        const float4 b = p4[2 * (size_t)r + 1];
        const int t = target[r];
        const float w = wlds[t];
        GHM_ROW
    }

    ghm_reduce_store(A0x, A1, A2, A3, A4, B0, B1, B2, B3, B4, sumw, ws, tid);
}

__global__ __launch_bounds__(BLOCK) void ghm_final(
    const float* __restrict__ ws, float* __restrict__ out, int nblocks)
{
    float u[20];
#pragma unroll
    for (int i = 0; i < 20; ++i) u[i] = 0.f;

    for (int b = threadIdx.x; b < nblocks; b += BLOCK) {
#pragma unroll
        for (int i = 0; i < 20; ++i) u[i] += ws[b * 32 + i];
    }

#pragma unroll
    for (int i = 0; i < 20; ++i) {
        float x = u[i];
#pragma unroll
        for (int o = 32; o >= 1; o >>= 1) x += __shfl_xor(x, o, 64);
        u[i] = x;
    }

    __shared__ float red[4][20];
    const int tid = threadIdx.x;
    const int lane = tid & 63, wv = tid >> 6;
    if (lane == 0) {
#pragma unroll
        for (int i = 0; i < 20; ++i) red[wv][i] = u[i];
    }
    __syncthreads();
    if (tid == 0) {
        float U[20];
#pragma unroll
        for (int i = 0; i < 20; ++i)
            U[i] = red[0][i] + red[1][i] + red[2][i] + red[3][i];

        // rebuild prefix tables
        // U: [0]=A0x [1..4]=Aix [5..9]=B0x..B4x [10]=sumw [11..14]=Aiy [15..19]=Biy
        const float tot = 33554432.0f; // N*C
        float T[21];
        T[0] = 0.5f * (U[0] + U[5]);  T[5] = 0.5f * (U[0] - U[5]);   // PhiPre0/PloPre0
#pragma unroll
        for (int i = 1; i < 5; ++i) {
            T[i]     = 0.5f * (U[i] + U[5 + i]);   // PhiPre_i
            T[5 + i] = 0.5f * (U[i] - U[5 + i]);   // PloPre_i
        }
        T[10] = 0.5f * (tot + U[15]);  T[15] = 0.5f * (tot - U[15]); // HiPre0/LoPre0
#pragma unroll
        for (int i = 1; i < 5; ++i) {
            const float all = U[10 + i];           // A_iy = gated count
            T[10 + i] = 0.5f * (all + U[15 + i]);  // HiPre_i
            T[15 + i] = 0.5f * (all - U[15 + i]);  // LoPre_i
        }
        T[20] = U[10];

        // differencing (identical to prior rounds)
        float S[10], CN[10];
#pragma unroll
        for (int k = 0; k < 5; ++k) {
            const float shn = (k < 4) ? T[k + 1]      : 0.f;
            const float sln = (k < 4) ? T[5 + k + 1]  : 0.f;
            const float chn = (k < 4) ? T[10 + k + 1] : 0.f;
            const float cln = (k < 4) ? T[15 + k + 1] : 0.f;
            S[9 - k] = T[k]     - shn;  CN[9 - k] = T[10 + k] - chn;
            S[k]     = T[5 + k] - sln;  CN[k]     = T[15 + k] - cln;
        }
        int nne = 0; float acc = 0.f;
#pragma unroll
        for (int i = 0; i < 10; ++i) {
            if (CN[i] > 0.5f) { nne++; acc += S[i] * (tot / CN[i]); }
        }
        out[0] = acc / (float)nne / (8.0f * T[20]);
    }
}

extern "C" void kernel_launch(void* const* d_in, const int* in_sizes, int n_in,
                              void* d_out, int out_size, void* d_ws, size_t ws_size,
                              hipStream_t stream) {
    const float* pred   = (const float*)d_in[0];
    const int*   target = (const int*)d_in[1];
    const float* weight = (const float*)d_in[2];
    float* out = (float*)d_out;

    int blocks;
    if (ws_size >= (size_t)MAXGRID * 128u) {
        blocks = MAXGRID;
        ghm_main_s<<<MAXGRID, BLOCK, 0, stream>>>(pred, target, weight, (float*)d_ws);
    } else {
        const int cap = (int)(ws_size / 128u);
        blocks = 1;
        while (blocks * 2 <= cap && blocks * 2 < MAXGRID) blocks *= 2; // pow2: exact divisibility
        ghm_main_d<<<blocks, BLOCK, 0, stream>>>(pred, target, weight, (float*)d_ws);
    }
    ghm_final<<<1, BLOCK, 0, stream>>>((const float*)d_ws, out, blocks);
}